// Round 1
// baseline (290.099 us; speedup 1.0000x reference)
//
#include <hip/hip_runtime.h>
#include <hip/hip_bf16.h>

#define NTOK    32768
#define DIMD    1024
#define RNK     128
#define NEXP    7
#define FULLKEY 7
#define TM      64
#define BK      128
#define MAXTILES (NTOK / TM)   // 512

using f32x4 = __attribute__((ext_vector_type(4))) float;
using s16x8 = __attribute__((ext_vector_type(8))) short;

__device__ __forceinline__ unsigned short f2bf(float f) {
    unsigned u = __float_as_uint(f);
    u += 0x7fffu + ((u >> 16) & 1u);   // RNE; inputs have no NaN
    return (unsigned short)(u >> 16);
}

__device__ __forceinline__ unsigned lra_bits(const int* __restrict__ mask) {
    unsigned bits = 0u;
#pragma unroll
    for (int i = 0; i < NEXP; ++i) {
        int m = mask[i];
        m = m < 0 ? 0 : (m > 7 ? 7 : m);
        bits |= (1u << m);
    }
    return bits;
}

// ---- convert f32 weights -> bf16 in workspace ----
__global__ void convert_weights(const float* __restrict__ Wd, const float* __restrict__ Wu,
                                unsigned short* __restrict__ WdB, unsigned short* __restrict__ WuB) {
    const int NE = NEXP * RNK * DIMD;              // 917504
    int i = (blockIdx.x * blockDim.x + threadIdx.x) * 4;
    const float* src;
    unsigned short* dst;
    int off;
    if (i < NE) { src = Wd; dst = WdB; off = i; }
    else        { src = Wu; dst = WuB; off = i - NE; }
    if (off < NE) {
        float4 v = *reinterpret_cast<const float4*>(src + off);
        ushort4 o;
        o.x = f2bf(v.x); o.y = f2bf(v.y); o.z = f2bf(v.z); o.w = f2bf(v.w);
        *reinterpret_cast<ushort4*>(dst + off) = o;
    }
}

// ---- bucket tokens by expert ----
__global__ void bucket_kernel(const int* __restrict__ ridx, const int* __restrict__ mask,
                              int* __restrict__ counts, int* __restrict__ bucket) {
    int t = blockIdx.x * blockDim.x + threadIdx.x;
    if (t >= NTOK) return;
    unsigned bits = lra_bits(mask);
    int k = ridx[t];
    if (k != FULLKEY && ((bits >> k) & 1u)) {
        int p = atomicAdd(&counts[k], 1);
        bucket[k * NTOK + p] = t;
    }
}

// ---- out = x for inactive tokens ----
__global__ void copy_inactive(const float* __restrict__ x, const int* __restrict__ ridx,
                              const int* __restrict__ mask, float* __restrict__ out) {
    unsigned bits = lra_bits(mask);
    for (int t = blockIdx.x; t < NTOK; t += gridDim.x) {
        int k = ridx[t];
        bool act = (k != FULLKEY) && ((bits >> k) & 1u);
        if (!act) {
            const float4* src = reinterpret_cast<const float4*>(x + (size_t)t * DIMD);
            float4* dst = reinterpret_cast<float4*>(out + (size_t)t * DIMD);
            dst[threadIdx.x] = src[threadIdx.x];   // 256 threads * 16B = 4KB row
        }
    }
}

// ---- fused per-expert: down = X*Wd^T ; up = down*Wu^T ; out = x + up ----
__launch_bounds__(256)
__global__ void expert_kernel(const float* __restrict__ x,
                              const unsigned short* __restrict__ WdB,
                              const unsigned short* __restrict__ WuB,
                              const int* __restrict__ counts,
                              const int* __restrict__ bucket,
                              float* __restrict__ out) {
    const int e = blockIdx.y;
    const int n = counts[e];
    const int base = blockIdx.x * TM;
    if (base >= n) return;
    const int nt = (TM < n - base) ? TM : (n - base);

    __shared__ int s_tid[TM];
    __shared__ unsigned short sX[TM * BK];    // 16 KB: phase1 X chunk, then down (bf16)
    __shared__ unsigned short sW[RNK * BK];   // 32 KB: Wd chunk / Wu chunk

    const int tid = threadIdx.x;
    if (tid < TM) {
        s_tid[tid] = bucket[e * NTOK + base + ((tid < nt) ? tid : 0)];
    }
    __syncthreads();

    const int w   = tid >> 6;
    const int l   = tid & 63;
    const int l15 = l & 15;
    const int lk  = l >> 4;

    char* sXb = reinterpret_cast<char*>(sX);
    char* sWb = reinterpret_cast<char*>(sW);

    const f32x4 zero = {0.f, 0.f, 0.f, 0.f};
    f32x4 accD[8];
#pragma unroll
    for (int i = 0; i < 8; ++i) accD[i] = zero;

    const unsigned short* We = WdB + (size_t)e * RNK * DIMD;

    // ---------- phase 1: down[64][128] = X * Wd^T ----------
    for (int kc = 0; kc < DIMD / BK; ++kc) {
        {   // stage X chunk [64 tokens][128 k] as bf16, XOR-swizzled
            const int row = tid >> 2;
            const float* src = x + (size_t)s_tid[row] * DIMD + kc * BK;
#pragma unroll
            for (int i = 0; i < 8; ++i) {
                const int c = (tid & 3) * 4 + i * 16;
                const float4 v = *reinterpret_cast<const float4*>(src + c);
                ushort4 o;
                o.x = f2bf(v.x); o.y = f2bf(v.y); o.z = f2bf(v.z); o.w = f2bf(v.w);
                const int byt = (row * 256 + c * 2) ^ ((row & 7) << 4);
                *reinterpret_cast<ushort4*>(sXb + byt) = o;
            }
        }
        {   // stage Wd chunk [128 rank][128 k] (already bf16), swizzled
            const int row = tid >> 1;
            const unsigned short* src = We + (size_t)row * DIMD + kc * BK;
#pragma unroll
            for (int i = 0; i < 8; ++i) {
                const int c = (tid & 1) * 8 + i * 16;
                const s16x8 v = *reinterpret_cast<const s16x8*>(src + c);
                const int byt = (row * 256 + c * 2) ^ ((row & 7) << 4);
                *reinterpret_cast<s16x8*>(sWb + byt) = v;
            }
        }
        __syncthreads();
#pragma unroll
        for (int ks = 0; ks < 4; ++ks) {
            const int arow = 16 * w + l15;
            const int ab = (arow * 256 + ks * 64 + lk * 16) ^ ((arow & 7) << 4);
            const s16x8 a = *reinterpret_cast<const s16x8*>(sXb + ab);
#pragma unroll
            for (int nn = 0; nn < 8; ++nn) {
                const int brow = 16 * nn + l15;
                const int bb = (brow * 256 + ks * 64 + lk * 16) ^ ((brow & 7) << 4);
                const s16x8 b = *reinterpret_cast<const s16x8*>(sWb + bb);
                accD[nn] = __builtin_amdgcn_mfma_f32_16x16x32_bf16(a, b, accD[nn], 0, 0, 0);
            }
        }
        __syncthreads();
    }

    // ---------- down -> sX as bf16 (swizzled). C layout: col=l&15, row=(l>>4)*4+j ----------
#pragma unroll
    for (int nn = 0; nn < 8; ++nn) {
#pragma unroll
        for (int j = 0; j < 4; ++j) {
            const int rowl = 16 * w + lk * 4 + j;
            const int col  = 16 * nn + l15;
            const int byt = (rowl * 256 + col * 2) ^ ((rowl & 7) << 4);
            *reinterpret_cast<unsigned short*>(sXb + byt) = f2bf(accD[nn][j]);
        }
    }
    __syncthreads();

    // hoist phase-2 A fragments (down rows for this wave) — sX is stable from here
    s16x8 a2[4];
#pragma unroll
    for (int ks = 0; ks < 4; ++ks) {
        const int arow = 16 * w + l15;
        const int ab = (arow * 256 + ks * 64 + lk * 16) ^ ((arow & 7) << 4);
        a2[ks] = *reinterpret_cast<const s16x8*>(sXb + ab);
    }

    const unsigned short* Wue = WuB + (size_t)e * DIMD * RNK;

    // ---------- phase 2: up[64][1024] = down * Wu^T ; out = x + up ----------
    for (int dc = 0; dc < DIMD / BK; ++dc) {
        {   // stage Wu chunk [128 dims][128 rank] — contiguous 32KB in global
            const unsigned short* src = Wue + (size_t)dc * BK * RNK;
#pragma unroll
            for (int it = 0; it < 8; ++it) {
                const int jj = (it * 256 + tid) * 8;
                const int rr = jj >> 7;
                const int cc = jj & 127;
                const s16x8 v = *reinterpret_cast<const s16x8*>(src + jj);
                const int byt = (rr * 256 + cc * 2) ^ ((rr & 7) << 4);
                *reinterpret_cast<s16x8*>(sWb + byt) = v;
            }
        }
        __syncthreads();
        f32x4 accU[8];
#pragma unroll
        for (int i = 0; i < 8; ++i) accU[i] = zero;
#pragma unroll
        for (int ks = 0; ks < 4; ++ks) {
#pragma unroll
            for (int nn = 0; nn < 8; ++nn) {
                const int brow = 16 * nn + l15;
                const int bb = (brow * 256 + ks * 64 + lk * 16) ^ ((brow & 7) << 4);
                const s16x8 b = *reinterpret_cast<const s16x8*>(sWb + bb);
                accU[nn] = __builtin_amdgcn_mfma_f32_16x16x32_bf16(a2[ks], b, accU[nn], 0, 0, 0);
            }
        }
        // epilogue: out = x + up (x read in f32, exact passthrough)
#pragma unroll
        for (int nn = 0; nn < 8; ++nn) {
#pragma unroll
            for (int j = 0; j < 4; ++j) {
                const int rowl = 16 * w + lk * 4 + j;
                if (rowl < nt) {
                    const size_t off = (size_t)s_tid[rowl] * DIMD + dc * BK + 16 * nn + l15;
                    out[off] = x[off] + accU[nn][j];
                }
            }
        }
        __syncthreads();
    }
}

extern "C" void kernel_launch(void* const* d_in, const int* in_sizes, int n_in,
                              void* d_out, int out_size, void* d_ws, size_t ws_size,
                              hipStream_t stream) {
    const float* x  = (const float*)d_in[0];
    const int* ridx = (const int*)d_in[1];
    const int* mask = (const int*)d_in[2];
    const float* Wd = (const float*)d_in[3];
    const float* Wu = (const float*)d_in[4];
    float* out = (float*)d_out;

    char* ws = (char*)d_ws;
    int* counts = (int*)ws;                                   // 32 B
    int* bucket = (int*)(ws + 256);                           // 7*32768*4 = 917504 B
    unsigned short* WdB = (unsigned short*)(ws + 917760);     // 1835008 B (16B-aligned)
    unsigned short* WuB = (unsigned short*)(ws + 2752768);    // 1835008 B (16B-aligned)

    hipMemsetAsync(counts, 0, 8 * sizeof(int), stream);
    convert_weights<<<dim3(1792), dim3(256), 0, stream>>>(Wd, Wu, WdB, WuB);
    bucket_kernel<<<dim3(128), dim3(256), 0, stream>>>(ridx, mask, counts, bucket);
    copy_inactive<<<dim3(2048), dim3(256), 0, stream>>>(x, ridx, mask, out);
    expert_kernel<<<dim3(MAXTILES, NEXP), dim3(256), 0, stream>>>(x, WdB, WuB, counts, bucket, out);
}